// Round 6
// baseline (146.733 us; speedup 1.0000x reference)
//
#include <hip/hip_runtime.h>
#include <cstdint>
#include <cstddef>

// ---------------------------------------------------------------------------
// RNN_No_FFNN: h_t = sigmoid(hidden@U_w.T + U_b + line@W_w.T + W_b)
//              pred = h_t@V_w.T + V_b ; out0 = segmented log_softmax(pred)
// B=8192, H=2048, D=104.  Outputs: [pred_logsoft (8192*104) | h_t (8192*2048)] f32.
// gemm1 (R6): 256x256 tile, BK=64, REGISTER-double-buffered fragments:
//   ds_reads for half-tile h+1 issue BEFORE the MFMA cluster of half-tile h
//   (compiler emits counted lgkmcnt -> LDS pipe drains under MFMA).
//   2 phases + 2 barriers per K-tile, counted vmcnt(8)/vmcnt(4) staging gates,
//   XOR slot swizzle (conflict-free, R4/R5-verified), 1 block/CU.
// ---------------------------------------------------------------------------

typedef __bf16 bf16x8 __attribute__((ext_vector_type(8)));
typedef float  f32x4  __attribute__((ext_vector_type(4)));
typedef unsigned short ushort8 __attribute__((ext_vector_type(8)));
typedef float  float4v __attribute__((ext_vector_type(4)));

#define BB 8192
#define HH 2048
#define DD 104

static __device__ __forceinline__ unsigned short f2bf(float f) {
  unsigned u = __float_as_uint(f);
  unsigned r = (u + 0x7FFFu + ((u >> 16) & 1u)) >> 16;  // RNE
  return (unsigned short)r;
}

#define GLD_LDS(g, l)                                                          \
  __builtin_amdgcn_global_load_lds(                                            \
      (__attribute__((address_space(1))) void*)(g),                            \
      (__attribute__((address_space(3))) void*)(l), 16, 0, 0)

#define MEMFENCE asm volatile("" ::: "memory")
#define MFMA16(a, b, c) __builtin_amdgcn_mfma_f32_16x16x32_bf16((a), (b), (c), 0, 0, 0)

// ---------------------------------------------------------------------------
// Conversion kernels (unchanged)
// ---------------------------------------------------------------------------
__global__ __launch_bounds__(256) void conv_bf16_kernel(
    const float* __restrict__ hidden, const float* __restrict__ Uw,
    unsigned short* __restrict__ out_hidden, unsigned short* __restrict__ out_U) {
  long long i = ((long long)blockIdx.x * blockDim.x + threadIdx.x) * 8;
  const float* src; unsigned short* dst; long long off;
  if (i < (long long)BB * HH) { src = hidden; dst = out_hidden; off = i; }
  else { src = Uw; dst = out_U; off = i - (long long)BB * HH; }
  float4v a = *(const float4v*)(src + off);
  float4v b = *(const float4v*)(src + off + 4);
  ushort8 o;
  o[0]=f2bf(a[0]); o[1]=f2bf(a[1]); o[2]=f2bf(a[2]); o[3]=f2bf(a[3]);
  o[4]=f2bf(b[0]); o[5]=f2bf(b[1]); o[6]=f2bf(b[2]); o[7]=f2bf(b[3]);
  *(ushort8*)(dst + off) = o;
}

__global__ __launch_bounds__(256) void pad_bf16_kernel(
    const float* __restrict__ line, const float* __restrict__ Ww,
    const float* __restrict__ Vw,
    unsigned short* __restrict__ line_pad, unsigned short* __restrict__ Ww_pad,
    unsigned short* __restrict__ Vw_pad) {
  int i = blockIdx.x * blockDim.x + threadIdx.x;
  const int N1 = BB * 128;          // 1048576
  const int N2 = N1 + HH * 128;     // +262144
  if (i < N1) {
    int r = i >> 7, c = i & 127;
    line_pad[i] = (c < DD) ? f2bf(line[r * DD + c]) : (unsigned short)0;
  } else if (i < N2) {
    int j = i - N1; int r = j >> 7, c = j & 127;
    Ww_pad[j] = (c < DD) ? f2bf(Ww[r * DD + c]) : (unsigned short)0;
  } else {
    int j = i - N2; int r = j >> 11, c = j & 2047;
    Vw_pad[j] = (r < DD) ? f2bf(Vw[r * 2048 + c]) : (unsigned short)0;
  }
}

// ---------------------------------------------------------------------------
// GEMM1 tile body. LDS per buf: A 16384 ush = [kh:2][row:256][4 slots x 8elem],
// B same at +32768; slot XOR-swizzled: LDS[kh][row][s] = G[row][kb+kh*32+(s^((row>>1)&3))*8].
// Staging chunk order: A-kh0 x2, B-kh0 x2, A-kh1 x2, B-kh1 x2 -> vmcnt(4)
// certifies exactly the kh0 half of tile t+1.
// Phase A: {GLD x8 (tile t+1 -> buf^1); vmcnt(8) [retire t's kh1, issued last
//   body]; barrier; ds_read kh1(t)->Rn; MFMA x32 on Rc (kh0 t)}.
// Phase B: {vmcnt(4) [t+1 kh0 landed]; barrier; ds_read kh0(t+1)->Rc;
//   MFMA x32 on Rn}. Reads precede the MFMA cluster that does NOT consume
//   them -> compiler emits counted lgkmcnt; LDS drains under MFMA.
// ---------------------------------------------------------------------------
template <int BUF, bool STAGE>
static __device__ __forceinline__ void tile_body(
    int kb_n, unsigned short* smem,
    const unsigned short* pAh, const unsigned short* pAl,
    const unsigned short* pBu, const unsigned short* pBw,
    unsigned short* dA, unsigned short* dB,
    int aoffs, int boffs,
    bf16x8 (&ac)[8], bf16x8 (&bc)[4], bf16x8 (&an)[8], bf16x8 (&bn)[4],
    f32x4 (&acc)[8][4]) {
  constexpr int SB = BUF ^ 1;
  const unsigned short* Ab  = smem + BUF * 16384;
  const unsigned short* Bb  = smem + 32768 + BUF * 16384;
  const unsigned short* Ab2 = smem + SB * 16384;
  const unsigned short* Bb2 = smem + 32768 + SB * 16384;

  // ---------- phase A ----------
  if constexpr (STAGE) {
    const bool hi = (kb_n >= 2048);
    const unsigned short* sA0 = hi ? pAl + (kb_n - 2048) : pAh + kb_n;
    const unsigned short* sB0 = hi ? pBw + (kb_n - 2048) : pBu + kb_n;
    const int rstr = hi ? 128 : 2048;
    GLD_LDS(sA0, dA + SB * 16384);
    GLD_LDS(sA0 + 128 * rstr, dA + SB * 16384 + 4096);
    GLD_LDS(sB0, dB + SB * 16384);
    GLD_LDS(sB0 + 128 * rstr, dB + SB * 16384 + 4096);
    GLD_LDS(sA0 + 32, dA + SB * 16384 + 8192);
    GLD_LDS(sA0 + 32 + 128 * rstr, dA + SB * 16384 + 8192 + 4096);
    GLD_LDS(sB0 + 32, dB + SB * 16384 + 8192);
    GLD_LDS(sB0 + 32 + 128 * rstr, dB + SB * 16384 + 8192 + 4096);
    asm volatile("s_waitcnt vmcnt(8)" ::: "memory");
  } else {
    asm volatile("s_waitcnt vmcnt(0)" ::: "memory");
  }
  MEMFENCE; __builtin_amdgcn_s_barrier(); MEMFENCE;
  // kh1 fragments of tile t (buf BUF) -> Rn (not consumed this phase)
#pragma unroll
  for (int mi = 0; mi < 8; ++mi)
    an[mi] = *(const bf16x8*)(Ab + 8192 + aoffs + mi * 512);
#pragma unroll
  for (int nf = 0; nf < 4; ++nf)
    bn[nf] = *(const bf16x8*)(Bb + 8192 + boffs + nf * 512);
  __builtin_amdgcn_s_setprio(1);
#pragma unroll
  for (int mi = 0; mi < 8; ++mi)
#pragma unroll
    for (int nf = 0; nf < 4; ++nf)
      acc[mi][nf] = MFMA16(ac[mi], bc[nf], acc[mi][nf]);
  __builtin_amdgcn_s_setprio(0);

  // ---------- phase B ----------
  if constexpr (STAGE) {
    asm volatile("s_waitcnt vmcnt(4)" ::: "memory");
  }
  MEMFENCE; __builtin_amdgcn_s_barrier(); MEMFENCE;
  if constexpr (STAGE) {
    // kh0 fragments of tile t+1 (buf SB, just confirmed) -> Rc
#pragma unroll
    for (int mi = 0; mi < 8; ++mi)
      ac[mi] = *(const bf16x8*)(Ab2 + aoffs + mi * 512);
#pragma unroll
    for (int nf = 0; nf < 4; ++nf)
      bc[nf] = *(const bf16x8*)(Bb2 + boffs + nf * 512);
  }
  __builtin_amdgcn_s_setprio(1);
#pragma unroll
  for (int mi = 0; mi < 8; ++mi)
#pragma unroll
    for (int nf = 0; nf < 4; ++nf)
      acc[mi][nf] = MFMA16(an[mi], bn[nf], acc[mi][nf]);
  __builtin_amdgcn_s_setprio(0);
}

__global__ __launch_bounds__(512, 2) void gemm1_kernel(
    const unsigned short* __restrict__ Ahid,   // [8192][2048] bf16
    const unsigned short* __restrict__ Aline,  // [8192][128]  bf16 (zero-pad)
    const unsigned short* __restrict__ BU,     // [2048][2048] bf16
    const unsigned short* __restrict__ BW,     // [2048][128]  bf16 (zero-pad)
    const float* __restrict__ Ub, const float* __restrict__ Wb,
    float* __restrict__ outH, unsigned short* __restrict__ outHbf) {
  __shared__ unsigned short smem[65536];   // 128 KB
  const int t = threadIdx.x;
  const int l = t & 63;
  const int wid = t >> 6;
  const int wr = wid >> 2, wc = wid & 3;   // 2 x 4 waves, 128x64 out each

  // bijective XCD-chunked swizzle: 256 wgs, 8 XCDs, 32/chunk
  const int bid = blockIdx.x;
  const int wg = (bid & 7) * 32 + (bid >> 3);
  const int brow = (wg >> 3) * 256;   // 32 M tiles
  const int bcol = (wg & 7) * 256;    // 8 N tiles

  const int frow = l & 15, lhi = l >> 4;
  const int slot8 = (lhi ^ ((frow >> 1) & 3)) * 8;   // swizzled read slot

  // staging: thread t -> rows t>>2 and t>>2+128; source col pre-swizzled
  const int srow = t >> 2;
  const int scol = (((t & 3) ^ ((t >> 3) & 3)) * 8);
  const unsigned short* pAh = Ahid + (size_t)(brow + srow) * 2048 + scol;
  const unsigned short* pAl = Aline + (size_t)(brow + srow) * 128 + scol;
  const unsigned short* pBu = BU + (size_t)(bcol + srow) * 2048 + scol;
  const unsigned short* pBw = BW + (size_t)(bcol + srow) * 128 + scol;
  unsigned short* dA = smem + t * 8;           // + SB*16384 + kh*8192 + j*4096
  unsigned short* dB = smem + 32768 + t * 8;

  const int aoffs = (wr * 128 + frow) * 32 + slot8;   // + kh*8192 + mi*512
  const int boffs = (wc * 64 + frow) * 32 + slot8;    // + kh*8192 + nf*512

  f32x4 acc[8][4] = {};

  // prologue: stage tile 0 -> buf0; drain; seed Rc with kh0(tile0)
  GLD_LDS(pAh, dA);
  GLD_LDS(pAh + 128 * 2048, dA + 4096);
  GLD_LDS(pBu, dB);
  GLD_LDS(pBu + 128 * 2048, dB + 4096);
  GLD_LDS(pAh + 32, dA + 8192);
  GLD_LDS(pAh + 32 + 128 * 2048, dA + 8192 + 4096);
  GLD_LDS(pBu + 32, dB + 8192);
  GLD_LDS(pBu + 32 + 128 * 2048, dB + 8192 + 4096);
  asm volatile("s_waitcnt vmcnt(0)" ::: "memory");
  MEMFENCE; __builtin_amdgcn_s_barrier(); MEMFENCE;

  bf16x8 ac[8], bc[4], an[8], bn[4];
#pragma unroll
  for (int mi = 0; mi < 8; ++mi)
    ac[mi] = *(const bf16x8*)(smem + aoffs + mi * 512);
#pragma unroll
  for (int nf = 0; nf < 4; ++nf)
    bc[nf] = *(const bf16x8*)(smem + 32768 + boffs + nf * 512);

  // K = 2176 = 34 tiles of 64 (2048 hidden/U_w + 128 line/W_w concat)
  for (int it = 0; it < 16; ++it) {
    tile_body<0, true>((2 * it + 1) * 64, smem, pAh, pAl, pBu, pBw, dA, dB,
                       aoffs, boffs, ac, bc, an, bn, acc);
    tile_body<1, true>((2 * it + 2) * 64, smem, pAh, pAl, pBu, pBw, dA, dB,
                       aoffs, boffs, ac, bc, an, bn, acc);
  }
  tile_body<0, true>(33 * 64, smem, pAh, pAl, pBu, pBw, dA, dB,
                     aoffs, boffs, ac, bc, an, bn, acc);
  tile_body<1, false>(0, smem, pAh, pAl, pBu, pBw, dA, dB,
                      aoffs, boffs, ac, bc, an, bn, acc);

  // epilogue: +bias, sigmoid, dual write (C/D: col = frow, row = lhi*4 + jj)
#pragma unroll
  for (int nf = 0; nf < 4; ++nf) {
    const int col = bcol + wc * 64 + nf * 16 + frow;
    const float bias = Ub[col] + Wb[col];
#pragma unroll
    for (int mi = 0; mi < 8; ++mi) {
      const int r0 = brow + wr * 128 + mi * 16 + lhi * 4;
#pragma unroll
      for (int jj = 0; jj < 4; ++jj) {
        const float v = acc[mi][nf][jj] + bias;
        const float h = 1.0f / (1.0f + __expf(-v));
        const size_t idx = (size_t)(r0 + jj) * HH + col;
        outH[idx] = h;
        outHbf[idx] = f2bf(h);
      }
    }
  }
}

// ---------------------------------------------------------------------------
// GEMM2 (unchanged): pred = h_t@V_w.T + V_b + fused seg log-softmax
// ---------------------------------------------------------------------------
template <int NM, int NN>
static __device__ __forceinline__ void mfma_step(
    const unsigned short* sA, const unsigned short* sB, int arow0, int brow0,
    int frow, int fk, f32x4 (&acc)[NM][NN]) {
  bf16x8 af[NM], bfr[NN];
#pragma unroll
  for (int m = 0; m < NM; ++m)
    af[m] = *(const bf16x8*)(sA + (arow0 + m * 16 + frow) * 32 + fk);
#pragma unroll
  for (int n = 0; n < NN; ++n)
    bfr[n] = *(const bf16x8*)(sB + (brow0 + n * 16 + frow) * 32 + fk);
#pragma unroll
  for (int m = 0; m < NM; ++m)
#pragma unroll
    for (int n = 0; n < NN; ++n)
      acc[m][n] = MFMA16(af[m], bfr[n], acc[m][n]);
}

__global__ __launch_bounds__(256, 2) void gemm2_kernel(
    const unsigned short* __restrict__ A,   // h_t bf16 [8192][2048]
    const unsigned short* __restrict__ Bm,  // Vw_pad [128][2048]
    const float* __restrict__ Vb,
    float* __restrict__ outLS) {            // [8192][104] f32
  __shared__ unsigned short sA[64 * 32];
  __shared__ unsigned short sB[128 * 32];
  __shared__ float pred[64 * 105];
  const int t = threadIdx.x;
  const int l = t & 63;
  const int wid = t >> 6, wr = wid >> 1, wc = wid & 1;
  const int brow = blockIdx.x * 64;
  const int srow = t >> 2, scg = t & 3;
  const int frow = l & 15, fk = (l >> 4) * 8;

  const unsigned short* gA = A + (size_t)(brow + srow) * HH + scg * 8;
  const unsigned short* gB = Bm + (size_t)srow * HH + scg * 8;
  unsigned short* lA = sA + t * 8;
  unsigned short* lB = sB + t * 8;

  f32x4 acc[2][4] = {};
  for (int ks = 0; ks < 64; ++ks) {
    __syncthreads();
    GLD_LDS(gA, lA);
    GLD_LDS(gB, lB);
    GLD_LDS(gB + 64 * HH, lB + 64 * 32);
    gA += 32; gB += 32;
    __syncthreads();
    mfma_step<2, 4>(sA, sB, wr * 32, wc * 64, frow, fk, acc);
  }

#pragma unroll
  for (int n = 0; n < 4; ++n) {
    const int col = wc * 64 + n * 16 + frow;
    if (col < DD) {
      const float vb = Vb[col];
#pragma unroll
      for (int m = 0; m < 2; ++m) {
        const int r0 = wr * 32 + m * 16 + (l >> 4) * 4;
#pragma unroll
        for (int j = 0; j < 4; ++j)
          pred[(r0 + j) * 105 + col] = acc[m][n][j] + vb;
      }
    }
  }
  __syncthreads();

  if (t < 64) {
    const int segb[11] = {0, 13, 26, 39, 48, 52, 65, 78, 91, 100, 104};
    const float* p = pred + t * 105;
    float* o = outLS + (size_t)(brow + t) * DD;
    for (int s = 0; s < 10; ++s) {
      const int a = segb[s], b = segb[s + 1];
      float mx = -3.0e38f;
      for (int c = a; c < b; ++c) mx = fmaxf(mx, p[c]);
      float sum = 0.0f;
      for (int c = a; c < b; ++c) sum += __expf(p[c] - mx);
      const float ls = __logf(sum) + mx;
      for (int c = a; c < b; ++c) o[c] = p[c] - ls;
    }
  }
}

// ---------------------------------------------------------------------------
// Launch
// ---------------------------------------------------------------------------
extern "C" void kernel_launch(void* const* d_in, const int* in_sizes, int n_in,
                              void* d_out, int out_size, void* d_ws, size_t ws_size,
                              hipStream_t stream) {
  (void)in_sizes; (void)n_in; (void)out_size; (void)ws_size;
  const float* line   = (const float*)d_in[0];
  const float* hidden = (const float*)d_in[1];
  const float* Uw     = (const float*)d_in[2];
  const float* Ub     = (const float*)d_in[3];
  const float* Ww     = (const float*)d_in[4];
  const float* Wb     = (const float*)d_in[5];
  const float* Vw     = (const float*)d_in[6];
  const float* Vb     = (const float*)d_in[7];

  char* ws = (char*)d_ws;
  unsigned short* hid_bf  = (unsigned short*)(ws);              // 33,554,432 B
  unsigned short* U_bf    = (unsigned short*)(ws + 33554432);   //  8,388,608
  unsigned short* line_bf = (unsigned short*)(ws + 41943040);   //  2,097,152
  unsigned short* Ww_bf   = (unsigned short*)(ws + 44040192);   //    524,288
  unsigned short* Vw_bf   = (unsigned short*)(ws + 44564480);   //    524,288
  unsigned short* ht_bf   = (unsigned short*)(ws + 45088768);   // 33,554,432

  float* outLS = (float*)d_out;                    // [8192][104]
  float* outH  = (float*)d_out + (size_t)BB * DD;  // [8192][2048]

  conv_bf16_kernel<<<10240, 256, 0, stream>>>(hidden, Uw, hid_bf, U_bf);
  pad_bf16_kernel<<<6144, 256, 0, stream>>>(line, Ww, Vw, line_bf, Ww_bf, Vw_bf);
  gemm1_kernel<<<256, 512, 0, stream>>>(hid_bf, line_bf, U_bf, Ww_bf, Ub, Wb,
                                        outH, ht_bf);
  gemm2_kernel<<<128, 256, 0, stream>>>(ht_bf, Vw_bf, Vb, outLS);
}

// Round 7
// 118.928 us; speedup vs baseline: 1.2338x; 1.2338x over previous
//
#include <hip/hip_runtime.h>
#include <cstdint>
#include <cstddef>

// ---------------------------------------------------------------------------
// RNN_No_FFNN: h_t = sigmoid(hidden@U_w.T + U_b + line@W_w.T + W_b)
//              pred = h_t@V_w.T + V_b ; out0 = segmented log_softmax(pred)
// B=8192, H=2048, D=104.  Outputs: [pred_logsoft (8192*104) | h_t (8192*2048)] f32.
// gemm1 (R7): MX-fp8 e4m3 with UNIT block scales via
//   mfma_scale_f32_32x32x64_f8f6f4 (K-tile=128 -> 17 tiles, 34 barriers total).
//   256x256 tile, 512 thr, 2x64KB LDS dbuf, counted vmcnt(8), XOR slot swizzle.
//   A/B k-layout is self-consistent (same bijection both sides) -> exact dot
//   regardless of HW k-ordering. C/D layout: m=(reg&3)+8*(reg>>2)+4*(l>>5),
//   n=l&31 (guide-verified, shape-determined for f8f6f4).
// gemm2: bf16 16x16x32 + fused segmented log-softmax (unchanged).
// ---------------------------------------------------------------------------

typedef __bf16 bf16x8 __attribute__((ext_vector_type(8)));
typedef float  f32x4  __attribute__((ext_vector_type(4)));
typedef float  f32x16 __attribute__((ext_vector_type(16)));
typedef int    i32x4  __attribute__((ext_vector_type(4)));
typedef int    i32x8  __attribute__((ext_vector_type(8)));
typedef unsigned short ushort8 __attribute__((ext_vector_type(8)));
typedef unsigned char  uchar8  __attribute__((ext_vector_type(8)));
typedef float  float4v __attribute__((ext_vector_type(4)));

#define BB 8192
#define HH 2048
#define DD 104

static __device__ __forceinline__ unsigned short f2bf(float f) {
  unsigned u = __float_as_uint(f);
  unsigned r = (u + 0x7FFFu + ((u >> 16) & 1u)) >> 16;  // RNE
  return (unsigned short)r;
}

// f32 -> OCP e4m3fn, RNE, saturate to 448. Subnormal grid 2^-9 via float2int_rn.
static __device__ __forceinline__ unsigned char f2fp8(float x) {
  unsigned u = __float_as_uint(x);
  unsigned s = (u >> 24) & 0x80u;
  float ax = fabsf(x);
  ax = fminf(ax, 448.0f);
  unsigned code;
  if (ax >= 0.015625f) {                    // normal: exp >= -6
    unsigned b = __float_as_uint(ax);
    unsigned lsb = (b >> 20) & 1u;
    b += 0x0007FFFFu + lsb;                 // RNE at mantissa bit 20
    unsigned e = (b >> 23) & 0xFFu;         // 121..135 after clamp
    code = ((e - 120u) << 3) | ((b >> 20) & 7u);
  } else {                                  // subnormal: step 2^-9 (carry into normal ok)
    code = (unsigned)__float2int_rn(ax * 512.0f);
  }
  return (unsigned char)(s | code);
}

// async global->LDS, 16B per lane (dest = wave-uniform base + lane*16: linear)
#define GLD_LDS(g, l)                                                          \
  __builtin_amdgcn_global_load_lds(                                            \
      (__attribute__((address_space(1))) void*)(g),                            \
      (__attribute__((address_space(3))) void*)(l), 16, 0, 0)

#define MEMFENCE asm volatile("" ::: "memory")
#define MFMA16(a, b, c) __builtin_amdgcn_mfma_f32_16x16x32_bf16((a), (b), (c), 0, 0, 0)

// ---------------------------------------------------------------------------
// Conversion kernels
// ---------------------------------------------------------------------------
// hidden (16777216) then U_w (4194304): f32 -> fp8 e4m3, 8 elems/thread
__global__ __launch_bounds__(256) void conv_fp8_kernel(
    const float* __restrict__ hidden, const float* __restrict__ Uw,
    unsigned char* __restrict__ out_h, unsigned char* __restrict__ out_u) {
  long long i = ((long long)blockIdx.x * blockDim.x + threadIdx.x) * 8;
  const float* src; unsigned char* dst; long long off;
  if (i < (long long)BB * HH) { src = hidden; dst = out_h; off = i; }
  else { src = Uw; dst = out_u; off = i - (long long)BB * HH; }
  float4v a = *(const float4v*)(src + off);
  float4v b = *(const float4v*)(src + off + 4);
  uchar8 o;
  o[0]=f2fp8(a[0]); o[1]=f2fp8(a[1]); o[2]=f2fp8(a[2]); o[3]=f2fp8(a[3]);
  o[4]=f2fp8(b[0]); o[5]=f2fp8(b[1]); o[6]=f2fp8(b[2]); o[7]=f2fp8(b[3]);
  *(uchar8*)(dst + off) = o;
}

// line[8192,104]->line8[8192,128] fp8; W_w[2048,104]->Ww8[2048,128] fp8;
// V_w[104,2048]->Vw_bf[128,2048] bf16 (zero pad everywhere)
__global__ __launch_bounds__(256) void pad_mixed_kernel(
    const float* __restrict__ line, const float* __restrict__ Ww,
    const float* __restrict__ Vw,
    unsigned char* __restrict__ line8, unsigned char* __restrict__ Ww8,
    unsigned short* __restrict__ Vw_bf) {
  int i = blockIdx.x * blockDim.x + threadIdx.x;
  const int N1 = BB * 128;          // 1048576
  const int N2 = N1 + HH * 128;     // 1310720
  if (i < N1) {
    int r = i >> 7, c = i & 127;
    line8[i] = (c < DD) ? f2fp8(line[r * DD + c]) : (unsigned char)0;
  } else if (i < N2) {
    int j = i - N1; int r = j >> 7, c = j & 127;
    Ww8[j] = (c < DD) ? f2fp8(Ww[r * DD + c]) : (unsigned char)0;
  } else {
    int j = i - N2; int r = j >> 11, c = j & 2047;
    Vw_bf[j] = (r < DD) ? f2bf(Vw[r * 2048 + c]) : (unsigned short)0;
  }
}

// ---------------------------------------------------------------------------
// GEMM1 (MX-fp8). LDS: A bufs [0,65536), B bufs [65536,131072); per buf 32KB =
// [row:256][8 slots x 16B], slot XOR-swizzled by row: LDS[row][s] holds
// G[row][kb + (s ^ (row&7))*16 ..+16]. Staging: thread t -> row t>>3 (+64p),
// source col ((t&7)^(row&7))*16, dest linear t*16 (both-sides involution).
// Fragment read (32x32x64): lane l, k-chunk c=l>>5, kstep s: 32B at slots
// {(s*2+c)*2, +1} ^ (row&7). Same bijection for A and B -> layout-proof.
// ---------------------------------------------------------------------------
static __device__ __forceinline__ i32x8 frd(const unsigned char* base, int row, int s2c) {
  const unsigned char* p = base + row * 128;
  const int rx = row & 7;
  i32x4 lo = *(const i32x4*)(p + ((((s2c) << 1)    ) ^ rx) * 16);
  i32x4 hi = *(const i32x4*)(p + ((((s2c) << 1) | 1) ^ rx) * 16);
  i32x8 r;
  r[0]=lo[0]; r[1]=lo[1]; r[2]=lo[2]; r[3]=lo[3];
  r[4]=hi[0]; r[5]=hi[1]; r[6]=hi[2]; r[7]=hi[3];
  return r;
}

__global__ __launch_bounds__(512, 2) void gemm1_kernel(
    const unsigned char* __restrict__ A8,   // hidden fp8 [8192][2048]
    const unsigned char* __restrict__ L8,   // line fp8 [8192][128] (zero-pad)
    const unsigned char* __restrict__ U8w,  // U_w fp8 [2048][2048]
    const unsigned char* __restrict__ W8w,  // W_w fp8 [2048][128] (zero-pad)
    const float* __restrict__ Ub, const float* __restrict__ Wb,
    float* __restrict__ outH, unsigned short* __restrict__ outHbf) {
  __shared__ unsigned char smem[131072];    // 128 KB
  const int t = threadIdx.x;
  const int l = t & 63;
  const int wid = t >> 6;
  const int wr = wid >> 2, wc = wid & 3;    // 2 x 4 waves, 128x64 out each

  // bijective XCD-chunked swizzle: 256 wgs, 8 XCDs, 32/chunk
  const int bid = blockIdx.x;
  const int wg = (bid & 7) * 32 + (bid >> 3);
  const int brow = (wg >> 3) * 256;   // 32 M tiles
  const int bcol = (wg & 7) * 256;    // 8 N tiles

  const int lr = l & 31;              // fragment row
  const int lc = l >> 5;              // k-chunk (32 elems)

  const int srow = t >> 3;
  const int scol = ((t & 7) ^ (srow & 7)) * 16;   // pre-swizzled source col
  const unsigned char* pA = A8 + (size_t)(brow + srow) * 2048 + scol;
  const unsigned char* pL = L8 + (size_t)(brow + srow) * 128 + scol;
  const unsigned char* pU = U8w + (size_t)(bcol + srow) * 2048 + scol;
  const unsigned char* pW = W8w + (size_t)(bcol + srow) * 128 + scol;
  unsigned char* dA = smem + t * 16;
  unsigned char* dB = smem + 65536 + t * 16;

  f32x16 acc[4][2] = {};

  auto stage = [&](int kt, int buf) {
    const int kb = kt * 128;
    if (kb < 2048) {
      const unsigned char* sa = pA + kb;
      const unsigned char* sb = pU + kb;
#pragma unroll
      for (int p = 0; p < 4; ++p) {
        GLD_LDS(sa + p * 64 * 2048, dA + buf * 32768 + p * 8192);
        GLD_LDS(sb + p * 64 * 2048, dB + buf * 32768 + p * 8192);
      }
    } else {  // K-tail: line/W_w pads (kb==2048, col base 0)
#pragma unroll
      for (int p = 0; p < 4; ++p) {
        GLD_LDS(pL + p * 64 * 128, dA + buf * 32768 + p * 8192);
        GLD_LDS(pW + p * 64 * 128, dB + buf * 32768 + p * 8192);
      }
    }
  };

  // prologue: stage K-tile 0 into buf 0
  stage(0, 0);

  // K = 2176 = 17 tiles of 128 (2048 hidden/U_w + 128 line/W_w concat)
  for (int kt = 0; kt < 17; ++kt) {
    const int cur = kt & 1;
    if (kt < 16) {
      stage(kt + 1, cur ^ 1);
      asm volatile("s_waitcnt vmcnt(8)" ::: "memory");  // tile kt landed; kt+1 in flight
    } else {
      asm volatile("s_waitcnt vmcnt(0)" ::: "memory");
    }
    MEMFENCE; __builtin_amdgcn_s_barrier(); MEMFENCE;

    const unsigned char* Ab = smem + cur * 32768;
    const unsigned char* Bb = smem + 65536 + cur * 32768;
#pragma unroll
    for (int s = 0; s < 2; ++s) {           // two K=64 MFMA steps
      i32x8 af[4], bfv[2];
#pragma unroll
      for (int m = 0; m < 4; ++m)
        af[m] = frd(Ab, wr * 128 + m * 32 + lr, s * 2 + lc);
#pragma unroll
      for (int n = 0; n < 2; ++n)
        bfv[n] = frd(Bb, wc * 64 + n * 32 + lr, s * 2 + lc);
      __builtin_amdgcn_s_setprio(1);
#pragma unroll
      for (int m = 0; m < 4; ++m)
#pragma unroll
        for (int n = 0; n < 2; ++n)
          acc[m][n] = __builtin_amdgcn_mfma_scale_f32_32x32x64_f8f6f4(
              af[m], bfv[n], acc[m][n], 0 /*fp8 A*/, 0 /*fp8 B*/,
              0, 0x7F7F7F7F /*unit scales A*/, 0, 0x7F7F7F7F /*unit scales B*/);
      __builtin_amdgcn_s_setprio(0);
    }
    MEMFENCE; __builtin_amdgcn_s_barrier(); MEMFENCE;  // protect buf reuse
  }

  // epilogue: +bias, sigmoid, dual write.
  // C/D 32x32: n = l&31, m = (reg&3) + 8*(reg>>2) + 4*(l>>5)
#pragma unroll
  for (int nf = 0; nf < 2; ++nf) {
    const int col = bcol + wc * 64 + nf * 32 + lr;
    const float bias = Ub[col] + Wb[col];
#pragma unroll
    for (int mf = 0; mf < 4; ++mf) {
#pragma unroll
      for (int reg = 0; reg < 16; ++reg) {
        const int row = brow + wr * 128 + mf * 32 + (reg & 3) + 8 * (reg >> 2) + 4 * lc;
        const float v = acc[mf][nf][reg] + bias;
        const float h = 1.0f / (1.0f + __expf(-v));
        const size_t idx = (size_t)row * HH + col;
        outH[idx] = h;
        outHbf[idx] = f2bf(h);
      }
    }
  }
}

// ---------------------------------------------------------------------------
// GEMM2 (unchanged, bf16): pred = h_t@V_w.T + V_b + fused seg log-softmax
// ---------------------------------------------------------------------------
template <int NM, int NN>
static __device__ __forceinline__ void mfma_step(
    const unsigned short* sA, const unsigned short* sB, int arow0, int brow0,
    int frow, int fk, f32x4 (&acc)[NM][NN]) {
  bf16x8 af[NM], bfr[NN];
#pragma unroll
  for (int m = 0; m < NM; ++m)
    af[m] = *(const bf16x8*)(sA + (arow0 + m * 16 + frow) * 32 + fk);
#pragma unroll
  for (int n = 0; n < NN; ++n)
    bfr[n] = *(const bf16x8*)(sB + (brow0 + n * 16 + frow) * 32 + fk);
#pragma unroll
  for (int m = 0; m < NM; ++m)
#pragma unroll
    for (int n = 0; n < NN; ++n)
      acc[m][n] = MFMA16(af[m], bfr[n], acc[m][n]);
}

__global__ __launch_bounds__(256, 2) void gemm2_kernel(
    const unsigned short* __restrict__ A,   // h_t bf16 [8192][2048]
    const unsigned short* __restrict__ Bm,  // Vw_bf [128][2048]
    const float* __restrict__ Vb,
    float* __restrict__ outLS) {            // [8192][104] f32
  __shared__ unsigned short sA[64 * 32];
  __shared__ unsigned short sB[128 * 32];
  __shared__ float pred[64 * 105];
  const int t = threadIdx.x;
  const int l = t & 63;
  const int wid = t >> 6, wr = wid >> 1, wc = wid & 1;
  const int brow = blockIdx.x * 64;
  const int srow = t >> 2, scg = t & 3;
  const int frow = l & 15, fk = (l >> 4) * 8;

  const unsigned short* gA = A + (size_t)(brow + srow) * HH + scg * 8;
  const unsigned short* gB = Bm + (size_t)srow * HH + scg * 8;
  unsigned short* lA = sA + t * 8;
  unsigned short* lB = sB + t * 8;

  f32x4 acc[2][4] = {};
  for (int ks = 0; ks < 64; ++ks) {
    __syncthreads();
    GLD_LDS(gA, lA);
    GLD_LDS(gB, lB);
    GLD_LDS(gB + 64 * HH, lB + 64 * 32);
    gA += 32; gB += 32;
    __syncthreads();
    mfma_step<2, 4>(sA, sB, wr * 32, wc * 64, frow, fk, acc);
  }

#pragma unroll
  for (int n = 0; n < 4; ++n) {
    const int col = wc * 64 + n * 16 + frow;
    if (col < DD) {
      const float vb = Vb[col];
#pragma unroll
      for (int m = 0; m < 2; ++m) {
        const int r0 = wr * 32 + m * 16 + (l >> 4) * 4;
#pragma unroll
        for (int j = 0; j < 4; ++j)
          pred[(r0 + j) * 105 + col] = acc[m][n][j] + vb;
      }
    }
  }
  __syncthreads();

  if (t < 64) {
    const int segb[11] = {0, 13, 26, 39, 48, 52, 65, 78, 91, 100, 104};
    const float* p = pred + t * 105;
    float* o = outLS + (size_t)(brow + t) * DD;
    for (int s = 0; s < 10; ++s) {
      const int a = segb[s], b = segb[s + 1];
      float mx = -3.0e38f;
      for (int c = a; c < b; ++c) mx = fmaxf(mx, p[c]);
      float sum = 0.0f;
      for (int c = a; c < b; ++c) sum += __expf(p[c] - mx);
      const float ls = __logf(sum) + mx;
      for (int c = a; c < b; ++c) o[c] = p[c] - ls;
    }
  }
}

// ---------------------------------------------------------------------------
// Launch
// ---------------------------------------------------------------------------
extern "C" void kernel_launch(void* const* d_in, const int* in_sizes, int n_in,
                              void* d_out, int out_size, void* d_ws, size_t ws_size,
                              hipStream_t stream) {
  (void)in_sizes; (void)n_in; (void)out_size; (void)ws_size;
  const float* line   = (const float*)d_in[0];
  const float* hidden = (const float*)d_in[1];
  const float* Uw     = (const float*)d_in[2];
  const float* Ub     = (const float*)d_in[3];
  const float* Ww     = (const float*)d_in[4];
  const float* Wb     = (const float*)d_in[5];
  const float* Vw     = (const float*)d_in[6];
  const float* Vb     = (const float*)d_in[7];

  char* ws = (char*)d_ws;
  // ws layout (bytes)
  unsigned char* hid8    = (unsigned char*)(ws);               // 16,777,216
  unsigned char* U8w     = (unsigned char*)(ws + 16777216);    //  4,194,304
  unsigned char* line8   = (unsigned char*)(ws + 20971520);    //  1,048,576
  unsigned char* Ww8     = (unsigned char*)(ws + 22020096);    //    262,144
  unsigned short* Vw_bf  = (unsigned short*)(ws + 22282240);   //    524,288
  unsigned short* ht_bf  = (unsigned short*)(ws + 22806528);   // 33,554,432

  float* outLS = (float*)d_out;                    // [8192][104]
  float* outH  = (float*)d_out + (size_t)BB * DD;  // [8192][2048]

  // (16777216 + 4194304)/8/256 = 10240 blocks, exact cover
  conv_fp8_kernel<<<10240, 256, 0, stream>>>(hidden, Uw, hid8, U8w);
  // (1048576 + 262144 + 262144)/256 = 6144 blocks, exact cover
  pad_mixed_kernel<<<6144, 256, 0, stream>>>(line, Ww, Vw, line8, Ww8, Vw_bf);
  gemm1_kernel<<<256, 512, 0, stream>>>(hid8, line8, U8w, Ww8, Ub, Wb,
                                        outH, ht_bf);
  gemm2_kernel<<<128, 256, 0, stream>>>(ht_bf, Vw_bf, Vb, outLS);
}

// Round 8
// 117.880 us; speedup vs baseline: 1.2448x; 1.0089x over previous
//
#include <hip/hip_runtime.h>
#include <cstdint>
#include <cstddef>

// ---------------------------------------------------------------------------
// RNN_No_FFNN: h_t = sigmoid(hidden@U_w.T + U_b + line@W_w.T + W_b)
//              pred = h_t@V_w.T + V_b ; out0 = segmented log_softmax(pred)
// B=8192, H=2048, D=104.  Outputs: [pred_logsoft (8192*104) | h_t (8192*2048)] f32.
// gemm1 (R8): MX-fp8 e4m3 (unit scales) mfma_scale_f32_32x32x64_f8f6f4.
//   128x128 tile, 256 thr (2x2 waves, 64x64/wave), BK=128, 2x32KB LDS dbuf
//   -> 64KB -> 2 blocks/CU (cross-block overlap). k-pair-major LDS layout
//   [pair:4][row:128][32B]: fragment reads are contiguous 1KB/wave ->
//   conflict-free by construction, no XOR. Counted vmcnt(8) depth-1 prefetch.
// gemm2: bf16 16x16x32 + fused segmented log-softmax (unchanged).
// ---------------------------------------------------------------------------

typedef __bf16 bf16x8 __attribute__((ext_vector_type(8)));
typedef float  f32x4  __attribute__((ext_vector_type(4)));
typedef float  f32x16 __attribute__((ext_vector_type(16)));
typedef int    i32x8  __attribute__((ext_vector_type(8)));
typedef unsigned short ushort8 __attribute__((ext_vector_type(8)));
typedef unsigned char  uchar8  __attribute__((ext_vector_type(8)));
typedef float  float4v __attribute__((ext_vector_type(4)));

#define BB 8192
#define HH 2048
#define DD 104

static __device__ __forceinline__ unsigned short f2bf(float f) {
  unsigned u = __float_as_uint(f);
  unsigned r = (u + 0x7FFFu + ((u >> 16) & 1u)) >> 16;  // RNE
  return (unsigned short)r;
}

// f32 -> OCP e4m3fn, RNE, saturate to 448. Subnormal grid 2^-9 via float2int_rn.
static __device__ __forceinline__ unsigned char f2fp8(float x) {
  unsigned u = __float_as_uint(x);
  unsigned s = (u >> 24) & 0x80u;
  float ax = fabsf(x);
  ax = fminf(ax, 448.0f);
  unsigned code;
  if (ax >= 0.015625f) {                    // normal: exp >= -6
    unsigned b = __float_as_uint(ax);
    unsigned lsb = (b >> 20) & 1u;
    b += 0x0007FFFFu + lsb;                 // RNE at mantissa bit 20
    unsigned e = (b >> 23) & 0xFFu;         // 121..135 after clamp
    code = ((e - 120u) << 3) | ((b >> 20) & 7u);
  } else {                                  // subnormal: step 2^-9 (carry into normal ok)
    code = (unsigned)__float2int_rn(ax * 512.0f);
  }
  return (unsigned char)(s | code);
}

// async global->LDS, 16B per lane (dest = wave-uniform base + lane*16: linear)
#define GLD_LDS(g, l)                                                          \
  __builtin_amdgcn_global_load_lds(                                            \
      (__attribute__((address_space(1))) void*)(g),                            \
      (__attribute__((address_space(3))) void*)(l), 16, 0, 0)

#define MEMFENCE asm volatile("" ::: "memory")
#define MFMA16(a, b, c) __builtin_amdgcn_mfma_f32_16x16x32_bf16((a), (b), (c), 0, 0, 0)

// ---------------------------------------------------------------------------
// Conversion kernels (unchanged from R7)
// ---------------------------------------------------------------------------
__global__ __launch_bounds__(256) void conv_fp8_kernel(
    const float* __restrict__ hidden, const float* __restrict__ Uw,
    unsigned char* __restrict__ out_h, unsigned char* __restrict__ out_u) {
  long long i = ((long long)blockIdx.x * blockDim.x + threadIdx.x) * 8;
  const float* src; unsigned char* dst; long long off;
  if (i < (long long)BB * HH) { src = hidden; dst = out_h; off = i; }
  else { src = Uw; dst = out_u; off = i - (long long)BB * HH; }
  float4v a = *(const float4v*)(src + off);
  float4v b = *(const float4v*)(src + off + 4);
  uchar8 o;
  o[0]=f2fp8(a[0]); o[1]=f2fp8(a[1]); o[2]=f2fp8(a[2]); o[3]=f2fp8(a[3]);
  o[4]=f2fp8(b[0]); o[5]=f2fp8(b[1]); o[6]=f2fp8(b[2]); o[7]=f2fp8(b[3]);
  *(uchar8*)(dst + off) = o;
}

__global__ __launch_bounds__(256) void pad_mixed_kernel(
    const float* __restrict__ line, const float* __restrict__ Ww,
    const float* __restrict__ Vw,
    unsigned char* __restrict__ line8, unsigned char* __restrict__ Ww8,
    unsigned short* __restrict__ Vw_bf) {
  int i = blockIdx.x * blockDim.x + threadIdx.x;
  const int N1 = BB * 128;          // 1048576
  const int N2 = N1 + HH * 128;     // 1310720
  if (i < N1) {
    int r = i >> 7, c = i & 127;
    line8[i] = (c < DD) ? f2fp8(line[r * DD + c]) : (unsigned char)0;
  } else if (i < N2) {
    int j = i - N1; int r = j >> 7, c = j & 127;
    Ww8[j] = (c < DD) ? f2fp8(Ww[r * DD + c]) : (unsigned char)0;
  } else {
    int j = i - N2; int r = j >> 11, c = j & 2047;
    Vw_bf[j] = (r < DD) ? f2bf(Vw[r * 2048 + c]) : (unsigned short)0;
  }
}

// ---------------------------------------------------------------------------
// GEMM1 (MX-fp8, R8). LDS: A bufs [0,32768), B bufs [32768,65536); per buf
// 16KB = [pair:4][row:128][32B], pair = 32B k-chunk index within the 128-K
// tile. LDS[pair][row] = G[row][kb + pair*32 .. +32].
// Staging: thread t -> (row = t>>1, half = t&1): source
// G[row][kb + q*32 + half*16], dest = q*4096 + t*16 (linear per wave).
// Fragment read: lane l (lr=l&31, lc=l>>5), k-step s: ONE contiguous 32B at
// (s*2+lc)*4096 + row*32 -> 32 lanes = 1KB contiguous = conflict-free.
// Same k-bijection for A and B -> dot product exact regardless of HW k-order
// (R7-validated). C/D 32x32: n = l&31, m = (reg&3)+8*(reg>>2)+4*(l>>5).
// ---------------------------------------------------------------------------
__global__ __launch_bounds__(256, 2) void gemm1_kernel(
    const unsigned char* __restrict__ A8,   // hidden fp8 [8192][2048]
    const unsigned char* __restrict__ L8,   // line fp8 [8192][128] (zero-pad)
    const unsigned char* __restrict__ U8w,  // U_w fp8 [2048][2048]
    const unsigned char* __restrict__ W8w,  // W_w fp8 [2048][128] (zero-pad)
    const float* __restrict__ Ub, const float* __restrict__ Wb,
    float* __restrict__ outH, unsigned short* __restrict__ outHbf) {
  __shared__ __attribute__((aligned(32))) unsigned char smem[65536];  // 64 KB
  const int t = threadIdx.x;
  const int l = t & 63;
  const int wid = t >> 6;
  const int wr = wid >> 1, wc = wid & 1;    // 2 x 2 waves, 64x64 out each

  // bijective XCD-chunked swizzle: 1024 wgs, 8 XCDs, 128/chunk
  const int bid = blockIdx.x;
  const int wg = (bid & 7) * 128 + (bid >> 3);
  const int brow = (wg >> 4) * 128;   // 64 M tiles
  const int bcol = (wg & 15) * 128;   // 16 N tiles

  const int lr = l & 31;              // fragment row within 32-row band
  const int lc = l >> 5;              // k-half-chunk select

  // staging addressing
  const int sr = t >> 1, sh = (t & 1) * 16;
  const unsigned char* pA = A8 + (size_t)(brow + sr) * 2048 + sh;
  const unsigned char* pL = L8 + (size_t)(brow + sr) * 128 + sh;
  const unsigned char* pU = U8w + (size_t)(bcol + sr) * 2048 + sh;
  const unsigned char* pW = W8w + (size_t)(bcol + sr) * 128 + sh;
  unsigned char* dA = smem + t * 16;            // + buf*16384 + q*4096
  unsigned char* dB = smem + 32768 + t * 16;

  f32x16 acc[2][2] = {};

  auto stage = [&](int kt, int buf) {
    const int kb = kt * 128;
    unsigned char* da = dA + buf * 16384;
    unsigned char* db = dB + buf * 16384;
    if (kb < 2048) {
#pragma unroll
      for (int q = 0; q < 4; ++q) {
        GLD_LDS(pA + kb + q * 32, da + q * 4096);
        GLD_LDS(pU + kb + q * 32, db + q * 4096);
      }
    } else {  // K-tail: line/W_w pads (row stride 128, col base 0)
#pragma unroll
      for (int q = 0; q < 4; ++q) {
        GLD_LDS(pL + q * 32, da + q * 4096);
        GLD_LDS(pW + q * 32, db + q * 4096);
      }
    }
  };

  // prologue: stage K-tile 0 into buf 0
  stage(0, 0);
  asm volatile("s_waitcnt vmcnt(0)" ::: "memory");
  MEMFENCE; __builtin_amdgcn_s_barrier(); MEMFENCE;

  // K = 2176 = 17 tiles of 128 (2048 hidden/U_w + 128 line/W_w concat)
  for (int kt = 0; kt < 17; ++kt) {
    const int cur = kt & 1;
    if (kt < 16) {
      stage(kt + 1, cur ^ 1);
      asm volatile("s_waitcnt vmcnt(8)" ::: "memory");  // tile kt fully landed
    } else {
      asm volatile("s_waitcnt vmcnt(0)" ::: "memory");
    }
    // NOTE: tile kt was already certified by the barrier below in iter kt-1;
    // the vmcnt here certifies nothing is outstanding INTO buf cur.
    const unsigned char* Ab = smem + cur * 16384;
    const unsigned char* Bb = smem + 32768 + cur * 16384;
#pragma unroll
    for (int s = 0; s < 2; ++s) {           // two K=64 MFMA steps
      const int pr = (s * 2 + lc) * 4096;
      i32x8 af[2], bfv[2];
#pragma unroll
      for (int m = 0; m < 2; ++m)
        af[m] = *(const i32x8*)(Ab + pr + (wr * 64 + m * 32 + lr) * 32);
#pragma unroll
      for (int n = 0; n < 2; ++n)
        bfv[n] = *(const i32x8*)(Bb + pr + (wc * 64 + n * 32 + lr) * 32);
      __builtin_amdgcn_s_setprio(1);
#pragma unroll
      for (int m = 0; m < 2; ++m)
#pragma unroll
        for (int n = 0; n < 2; ++n)
          acc[m][n] = __builtin_amdgcn_mfma_scale_f32_32x32x64_f8f6f4(
              af[m], bfv[n], acc[m][n], 0 /*fp8 A*/, 0 /*fp8 B*/,
              0, 0x7F7F7F7F /*unit scales A*/, 0, 0x7F7F7F7F /*unit scales B*/);
      __builtin_amdgcn_s_setprio(0);
    }
    MEMFENCE; __builtin_amdgcn_s_barrier(); MEMFENCE;  // reads done -> buf reusable
  }

  // epilogue: +bias, sigmoid, dual write.
  // C/D 32x32: n = l&31, m = (reg&3) + 8*(reg>>2) + 4*(l>>5)
#pragma unroll
  for (int nf = 0; nf < 2; ++nf) {
    const int col = bcol + wc * 64 + nf * 32 + lr;
    const float bias = Ub[col] + Wb[col];
#pragma unroll
    for (int mf = 0; mf < 2; ++mf) {
#pragma unroll
      for (int reg = 0; reg < 16; ++reg) {
        const int row = brow + wr * 64 + mf * 32 + (reg & 3) + 8 * (reg >> 2) + 4 * lc;
        const float v = acc[mf][nf][reg] + bias;
        const float h = 1.0f / (1.0f + __expf(-v));
        const size_t idx = (size_t)row * HH + col;
        outH[idx] = h;
        outHbf[idx] = f2bf(h);
      }
    }
  }
}

// ---------------------------------------------------------------------------
// GEMM2 (unchanged, bf16): pred = h_t@V_w.T + V_b + fused seg log-softmax
// ---------------------------------------------------------------------------
template <int NM, int NN>
static __device__ __forceinline__ void mfma_step(
    const unsigned short* sA, const unsigned short* sB, int arow0, int brow0,
    int frow, int fk, f32x4 (&acc)[NM][NN]) {
  bf16x8 af[NM], bfr[NN];
#pragma unroll
  for (int m = 0; m < NM; ++m)
    af[m] = *(const bf16x8*)(sA + (arow0 + m * 16 + frow) * 32 + fk);
#pragma unroll
  for (int n = 0; n < NN; ++n)
    bfr[n] = *(const bf16x8*)(sB + (brow0 + n * 16 + frow) * 32 + fk);
#pragma unroll
  for (int m = 0; m < NM; ++m)
#pragma unroll
    for (int n = 0; n < NN; ++n)
      acc[m][n] = MFMA16(af[m], bfr[n], acc[m][n]);
}

__global__ __launch_bounds__(256, 2) void gemm2_kernel(
    const unsigned short* __restrict__ A,   // h_t bf16 [8192][2048]
    const unsigned short* __restrict__ Bm,  // Vw_bf [128][2048]
    const float* __restrict__ Vb,
    float* __restrict__ outLS) {            // [8192][104] f32
  __shared__ unsigned short sA[64 * 32];
  __shared__ unsigned short sB[128 * 32];
  __shared__ float pred[64 * 105];
  const int t = threadIdx.x;
  const int l = t & 63;
  const int wid = t >> 6, wr = wid >> 1, wc = wid & 1;
  const int brow = blockIdx.x * 64;
  const int srow = t >> 2, scg = t & 3;
  const int frow = l & 15, fk = (l >> 4) * 8;

  const unsigned short* gA = A + (size_t)(brow + srow) * HH + scg * 8;
  const unsigned short* gB = Bm + (size_t)srow * HH + scg * 8;
  unsigned short* lA = sA + t * 8;
  unsigned short* lB = sB + t * 8;

  f32x4 acc[2][4] = {};
  for (int ks = 0; ks < 64; ++ks) {
    __syncthreads();
    GLD_LDS(gA, lA);
    GLD_LDS(gB, lB);
    GLD_LDS(gB + 64 * HH, lB + 64 * 32);
    gA += 32; gB += 32;
    __syncthreads();
    mfma_step<2, 4>(sA, sB, wr * 32, wc * 64, frow, fk, acc);
  }

#pragma unroll
  for (int n = 0; n < 4; ++n) {
    const int col = wc * 64 + n * 16 + frow;
    if (col < DD) {
      const float vb = Vb[col];
#pragma unroll
      for (int m = 0; m < 2; ++m) {
        const int r0 = wr * 32 + m * 16 + (l >> 4) * 4;
#pragma unroll
        for (int j = 0; j < 4; ++j)
          pred[(r0 + j) * 105 + col] = acc[m][n][j] + vb;
      }
    }
  }
  __syncthreads();

  if (t < 64) {
    const int segb[11] = {0, 13, 26, 39, 48, 52, 65, 78, 91, 100, 104};
    const float* p = pred + t * 105;
    float* o = outLS + (size_t)(brow + t) * DD;
    for (int s = 0; s < 10; ++s) {
      const int a = segb[s], b = segb[s + 1];
      float mx = -3.0e38f;
      for (int c = a; c < b; ++c) mx = fmaxf(mx, p[c]);
      float sum = 0.0f;
      for (int c = a; c < b; ++c) sum += __expf(p[c] - mx);
      const float ls = __logf(sum) + mx;
      for (int c = a; c < b; ++c) o[c] = p[c] - ls;
    }
  }
}

// ---------------------------------------------------------------------------
// Launch
// ---------------------------------------------------------------------------
extern "C" void kernel_launch(void* const* d_in, const int* in_sizes, int n_in,
                              void* d_out, int out_size, void* d_ws, size_t ws_size,
                              hipStream_t stream) {
  (void)in_sizes; (void)n_in; (void)out_size; (void)ws_size;
  const float* line   = (const float*)d_in[0];
  const float* hidden = (const float*)d_in[1];
  const float* Uw     = (const float*)d_in[2];
  const float* Ub     = (const float*)d_in[3];
  const float* Ww     = (const float*)d_in[4];
  const float* Wb     = (const float*)d_in[5];
  const float* Vw     = (const float*)d_in[6];
  const float* Vb     = (const float*)d_in[7];

  char* ws = (char*)d_ws;
  unsigned char* hid8    = (unsigned char*)(ws);               // 16,777,216
  unsigned char* U8w     = (unsigned char*)(ws + 16777216);    //  4,194,304
  unsigned char* line8   = (unsigned char*)(ws + 20971520);    //  1,048,576
  unsigned char* Ww8     = (unsigned char*)(ws + 22020096);    //    262,144
  unsigned short* Vw_bf  = (unsigned short*)(ws + 22282240);   //    524,288
  unsigned short* ht_bf  = (unsigned short*)(ws + 22806528);   // 33,554,432

  float* outLS = (float*)d_out;                    // [8192][104]
  float* outH  = (float*)d_out + (size_t)BB * DD;  // [8192][2048]

  conv_fp8_kernel<<<10240, 256, 0, stream>>>(hidden, Uw, hid8, U8w);
  pad_mixed_kernel<<<6144, 256, 0, stream>>>(line, Ww, Vw, line8, Ww8, Vw_bf);
  gemm1_kernel<<<1024, 256, 0, stream>>>(hid8, line8, U8w, Ww8, Ub, Wb,
                                         outH, ht_bf);
  gemm2_kernel<<<128, 256, 0, stream>>>(ht_bf, Vw_bf, Vb, outLS);
}